// Round 5
// baseline (173.652 us; speedup 1.0000x reference)
//
#include <hip/hip_runtime.h>
#include <hip/hip_bf16.h>

// PCNN recurrence, wave-synchronous v4.
// One WAVE owns R=256 region elems (C=128 stored + 64-halo each side, halo>=T
// so waves are independent — no barriers, no LDS arrays). Lane i holds region
// elems {2i,2i+1} (slot0) and {128+2i,128+2i+1} (slot1) as float2.
// Exchange = 4 ds_bpermute/step, in-register.
//
// v4 root-cause fix: rounds 3/4 showed VGPR_Count=32/44 — too small to hold
// the prefetch ring, i.e. the COMPILER SANK THE PREFETCH LOADS to their use
// sites (effective distance ~0), exposing ~500-900cyc L3/HBM latency per step
// with only 2 waves/SIMD => ~1900cyc/step. Fix: volatile loads — LLVM cannot
// reorder/sink volatile memory ops, so row t+8's loads stay issued at step t.
// Also: nontemporal stores restored (round 3 vs 4 A/B: plain stores pollute
// L2, FETCH 43->45.6MB and +5us).

#define TT 64
#define LL 8192
#define CC 128
#define HH 64
#define NCHUNK 64   // LL / CC

typedef float v2f __attribute__((ext_vector_type(2)));

__device__ __forceinline__ v2f vload(const float* p) {
    return *(const volatile v2f*)p;   // pinned: cannot be sunk by scheduler
}
__device__ __forceinline__ float bperm(int idx, float v) {
    return __int_as_float(__builtin_amdgcn_ds_bpermute(idx, __float_as_int(v)));
}
__device__ __forceinline__ float fsigmoid(float z) {
    return __fdividef(1.0f, 1.0f + __expf(-z));
}

__global__ __launch_bounds__(256) void pcnn5_kernel(
    const float* __restrict__ x, const float* __restrict__ wptr,
    float* __restrict__ out)
{
    const int lane = threadIdx.x & 63;
    const int tile = blockIdx.x * 4 + (threadIdx.x >> 6);  // 2048 wave-tiles
    const int chunk = tile & (NCHUNK - 1);
    const int b     = tile >> 6;

    const float w0 = wptr[0], w1 = wptr[1], w2 = wptr[2];
    const float df = 0.90483741803595957f;  // exp(-0.1)
    const float dl = 0.36787944117144233f;  // exp(-1)
    const float de = 0.36787944117144233f;

    const int r0 = 2 * lane;                 // slot0 region idx; slot1 = r0+128
    const int c0 = chunk * CC - HH + r0;     // global col, slot0
    const int c1 = c0 + 128;                 // global col, slot1
    const bool vz0 = ((unsigned)c0 < (unsigned)LL);
    const bool vz1 = ((unsigned)c1 < (unsigned)LL);
    const int cc0 = min(max(c0, 0), LL - 2); // clamped (always-safe) load cols
    const int cc1 = min(max(c1, 0), LL - 2);

    const float* xbase = x + (size_t)b * TT * LL;
    const float* xp0 = xbase + cc0;
    const float* xp1 = xbase + cc1;

    // merged store: lanes 0..31 write slot1, lanes 32..63 write slot0 —
    // one contiguous 512B segment, always in-bounds, unconditional.
    const bool lo = (lane < 32);
    float* op = out + (size_t)b * TT * LL + (lo ? c1 : c0);

    const int lm1 = ((lane + 63) & 63) << 2;  // bpermute byte idx: pull lane-1
    const int lp1 = ((lane + 1) & 63) << 2;   // pull lane+1

    // 8-deep prefetch ring: rows t..t+7 (compile-time indices only)
    v2f p0[8], p1[8];
    #pragma unroll
    for (int j = 0; j < 8; ++j) {
        p0[j] = vload(xp0 + (size_t)j * LL);
        p1[j] = vload(xp1 + (size_t)j * LL);
    }

    v2f f0 = {0.f, 0.f}, f1 = {0.f, 0.f};
    v2f l0 = {0.f, 0.f}, l1 = {0.f, 0.f};
    v2f e0 = {10.f, 10.f}, e1 = {10.f, 10.f};
    v2f y0 = {0.f, 0.f}, y1 = {0.f, 0.f};

    auto step = [&](v2f xa, v2f xb) {
        // neighbor exchange (old y)
        float rl0 = bperm(lm1, y0.y), rl1 = bperm(lm1, y1.y);
        float rr0 = bperm(lp1, y0.x), rr1 = bperm(lp1, y1.x);
        float yl0 = (lane == 0)  ? 0.f : rl0;
        float yl1 = (lane == 0)  ? rl0 : rl1;  // lane0 slot1 left = slot0 ln63 .y
        float yr1 = (lane == 63) ? 0.f : rr1;
        float yr0 = (lane == 63) ? rr1 : rr0;  // lane63 slot0 right = slot1 ln0 .x

        f0.x = df * f0.x + xa.x + (w0 * yl0  + w1 * y0.x + w2 * y0.y);
        f0.y = df * f0.y + xa.y + (w0 * y0.x + w1 * y0.y + w2 * yr0);
        f1.x = df * f1.x + xb.x + (w0 * yl1  + w1 * y1.x + w2 * y1.y);
        f1.y = df * f1.y + xb.y + (w0 * y1.x + w1 * y1.y + w2 * yr1);
        l0.x = dl * l0.x + (yl0  + y0.y);
        l0.y = dl * l0.y + (y0.x + yr0);
        l1.x = dl * l1.x + (yl1  + y1.y);
        l1.y = dl * l1.y + (y1.x + yr1);
        float u00 = f0.x * (1.0f + 0.5f * l0.x);
        float u01 = f0.y * (1.0f + 0.5f * l0.y);
        float u10 = f1.x * (1.0f + 0.5f * l1.x);
        float u11 = f1.y * (1.0f + 0.5f * l1.y);
        e0.x = de * e0.x + 10.0f * y0.x;
        e0.y = de * e0.y + 10.0f * y0.y;
        e1.x = de * e1.x + 10.0f * y1.x;
        e1.y = de * e1.y + 10.0f * y1.y;
        y0.x = vz0 ? fsigmoid(u00 - e0.x) : 0.f;
        y0.y = vz0 ? fsigmoid(u01 - e0.y) : 0.f;
        y1.x = vz1 ? fsigmoid(u10 - e1.x) : 0.f;
        y1.y = vz1 ? fsigmoid(u11 - e1.y) : 0.f;

        v2f yst;
        yst.x = lo ? y1.x : y0.x;
        yst.y = lo ? y1.y : y0.y;
        __builtin_nontemporal_store(yst, (v2f*)op);
        op += LL;
    };

    const float* xl0 = xp0 + 8 * (size_t)LL;  // row t+8 at loop top
    const float* xl1 = xp1 + 8 * (size_t)LL;

    for (int t = 0; t < TT; t += 8) {
        // loads in this iteration target rows t+8..t+15; valid iff t+16 <= TT.
        // Last outer iteration: redirect to row 0 (dummy, never consumed).
        const float* a0 = (t + 16 <= TT) ? xl0 : xp0;
        const float* a1 = (t + 16 <= TT) ? xl1 : xp1;
        #pragma unroll
        for (int j = 0; j < 8; ++j) {
            step(p0[j], p1[j]);
            p0[j] = vload(a0 + (size_t)j * LL);
            p1[j] = vload(a1 + (size_t)j * LL);
        }
        xl0 += 8 * (size_t)LL;
        xl1 += 8 * (size_t)LL;
    }
}

extern "C" void kernel_launch(void* const* d_in, const int* in_sizes, int n_in,
                              void* d_out, int out_size, void* d_ws, size_t ws_size,
                              hipStream_t stream) {
    const float* x = (const float*)d_in[0];
    const float* w = (const float*)d_in[1];
    float* out = (float*)d_out;
    // 2048 wave-tiles = 512 blocks x 4 waves; no LDS, no barriers.
    pcnn5_kernel<<<dim3(512), dim3(256), 0, stream>>>(x, w, out);
}

// Round 7
// 155.906 us; speedup vs baseline: 1.1138x; 1.1138x over previous
//
#include <hip/hip_runtime.h>
#include <hip/hip_bf16.h>

// PCNN recurrence, wave-synchronous v5b: async DMA x-pipeline.
// One WAVE owns R=256 region elems (C=128 stored + 64-halo each side; halo>=T
// so waves are fully independent — no barriers). Lane i holds region elems
// {2i,2i+1} (slot0) and {128+2i,128+2i+1} (slot1); exchange = 4 ds_bpermute.
//
// Rounds 3-5: compiler refuses to keep a VGPR prefetch ring alive (VGPR stuck
// at 32/44 => loads sunk to use sites => ~900cyc exposed latency/step).
// v5: x rows stream into a wave-PRIVATE 8-row LDS ring via
// __builtin_amdgcn_global_load_lds (1 row = 1024B = one width-16 DMA/wave).
// Side-effecting intrinsic -> cannot be sunk; no implicit vmcnt(0) for LDS
// reads -> we control the pipeline with explicit s_waitcnt vmcnt(N).
// Per step exactly 1 NT store + 1 DMA enter the vm FIFO, so row t is complete
// once <=12 newer entries remain; first 8 steps peeled with literal counts
// (builtin requires a literal -> manual peel, round-6 compile fix).

#define TT 64
#define LL 8192
#define CC 128
#define HH 64
#define NCHUNK 64   // LL / CC

typedef float v2f __attribute__((ext_vector_type(2)));

__device__ __forceinline__ void async_row_load(const float* g, float* l) {
    __builtin_amdgcn_global_load_lds(
        (const __attribute__((address_space(1))) unsigned int*)g,
        (__attribute__((address_space(3))) unsigned int*)l, 16, 0, 0);
}
// s_waitcnt imm (gfx9): vmcnt[3:0] | expcnt<<4 | lgkmcnt<<8 (lgkm=15,exp=7: no wait)
#define WAIT_VM(n) __builtin_amdgcn_s_waitcnt(0x0F70 | (n))

__device__ __forceinline__ float bperm(int idx, float v) {
    return __int_as_float(__builtin_amdgcn_ds_bpermute(idx, __float_as_int(v)));
}
__device__ __forceinline__ float fsigmoid(float z) {
    return __fdividef(1.0f, 1.0f + __expf(-z));
}

__global__ __launch_bounds__(256) void pcnn6_kernel(
    const float* __restrict__ x, const float* __restrict__ wptr,
    float* __restrict__ out)
{
    __shared__ __align__(16) float xs[4][8][256];   // per-wave 8-row ring

    const int lane = threadIdx.x & 63;
    const int w    = threadIdx.x >> 6;
    const int tile = blockIdx.x * 4 + w;            // 2048 wave-tiles
    const int chunk = tile & (NCHUNK - 1);
    const int b     = tile >> 6;

    const float w0 = wptr[0], w1 = wptr[1], w2 = wptr[2];
    const float df = 0.90483741803595957f;  // exp(-0.1)
    const float dl = 0.36787944117144233f;  // exp(-1)
    const float de = 0.36787944117144233f;

    const int r0 = 2 * lane;                 // slot0 region idx; slot1 = r0+128
    const int gbase = chunk * CC - HH;       // region covers cols [gbase, gbase+256)
    const int c0 = gbase + r0;
    const int c1 = c0 + 128;
    const bool vz0 = ((unsigned)c0 < (unsigned)LL);
    const bool vz1 = ((unsigned)c1 < (unsigned)LL);

    // clamped DMA source: one contiguous 1024B row inside [0, LL)
    const int cb = min(max(gbase, 0), LL - 256);   // multiple of 64 -> 256B aligned
    const int sh = gbase - cb;                     // -64 / 0 / +64
    // LDS idx of region elem r is r + sh; clamp to [0,254] (even; garbage is fine
    // for invalid lanes whose y is forced to 0)
    const int i0 = min(max(r0 + sh, 0), 254);
    const int i1 = min(max(r0 + 128 + sh, 0), 254);

    const float* xbase = x + (size_t)b * TT * LL;
    const float* xg = xbase + cb + 4 * lane;       // per-lane 16B segment

    // merged store: lanes 0..31 write slot1, lanes 32..63 write slot0 —
    // one contiguous 512B segment, always in-bounds.
    const bool lo = (lane < 32);
    float* op = out + (size_t)b * TT * LL + (lo ? c1 : c0);

    const int lm1 = ((lane + 63) & 63) << 2;  // bpermute: pull lane-1
    const int lp1 = ((lane + 1) & 63) << 2;   // pull lane+1

    v2f f0 = {0.f, 0.f}, f1 = {0.f, 0.f};
    v2f l0 = {0.f, 0.f}, l1 = {0.f, 0.f};
    v2f e0 = {10.f, 10.f}, e1 = {10.f, 10.f};
    v2f y0 = {0.f, 0.f}, y1 = {0.f, 0.f};

    auto step = [&](v2f xa, v2f xb) {
        float rl0 = bperm(lm1, y0.y), rl1 = bperm(lm1, y1.y);
        float rr0 = bperm(lp1, y0.x), rr1 = bperm(lp1, y1.x);
        float yl0 = (lane == 0)  ? 0.f : rl0;
        float yl1 = (lane == 0)  ? rl0 : rl1;
        float yr1 = (lane == 63) ? 0.f : rr1;
        float yr0 = (lane == 63) ? rr1 : rr0;

        f0.x = df * f0.x + xa.x + (w0 * yl0  + w1 * y0.x + w2 * y0.y);
        f0.y = df * f0.y + xa.y + (w0 * y0.x + w1 * y0.y + w2 * yr0);
        f1.x = df * f1.x + xb.x + (w0 * yl1  + w1 * y1.x + w2 * y1.y);
        f1.y = df * f1.y + xb.y + (w0 * y1.x + w1 * y1.y + w2 * yr1);
        l0.x = dl * l0.x + (yl0  + y0.y);
        l0.y = dl * l0.y + (y0.x + yr0);
        l1.x = dl * l1.x + (yl1  + y1.y);
        l1.y = dl * l1.y + (y1.x + yr1);
        float u00 = f0.x * (1.0f + 0.5f * l0.x);
        float u01 = f0.y * (1.0f + 0.5f * l0.y);
        float u10 = f1.x * (1.0f + 0.5f * l1.x);
        float u11 = f1.y * (1.0f + 0.5f * l1.y);
        e0.x = de * e0.x + 10.0f * y0.x;
        e0.y = de * e0.y + 10.0f * y0.y;
        e1.x = de * e1.x + 10.0f * y1.x;
        e1.y = de * e1.y + 10.0f * y1.y;
        y0.x = vz0 ? fsigmoid(u00 - e0.x) : 0.f;
        y0.y = vz0 ? fsigmoid(u01 - e0.y) : 0.f;
        y1.x = vz1 ? fsigmoid(u10 - e1.x) : 0.f;
        y1.y = vz1 ? fsigmoid(u11 - e1.y) : 0.f;

        v2f yst;
        yst.x = lo ? y1.x : y0.x;
        yst.y = lo ? y1.y : y0.y;
        __builtin_nontemporal_store(yst, (v2f*)op);
        op += LL;
    };

    // consume LDS row slot j, then issue DMA for row r into slot (j+7)&7
    auto consume_and_issue = [&](int j, int r) {
        v2f xa = *(const v2f*)&xs[w][j][i0];
        v2f xb = *(const v2f*)&xs[w][j][i1];
        step(xa, xb);
        const float* g = (r < TT) ? (xg + (size_t)r * LL) : xg;  // dummy ok
        async_row_load(g, &xs[w][(j + 7) & 7][0]);
    };

    // prologue: DMA rows 0..6 into slots 0..6
    #pragma unroll
    for (int j = 0; j < 7; ++j)
        async_row_load(xg + (size_t)j * LL, &xs[w][j][0]);

    // peeled first outer iteration (t=0..7): literal vmcnt counts
    WAIT_VM(6);  consume_and_issue(0, 7);
    WAIT_VM(7);  consume_and_issue(1, 8);
    WAIT_VM(8);  consume_and_issue(2, 9);
    WAIT_VM(9);  consume_and_issue(3, 10);
    WAIT_VM(10); consume_and_issue(4, 11);
    WAIT_VM(11); consume_and_issue(5, 12);
    WAIT_VM(12); consume_and_issue(6, 13);
    WAIT_VM(12); consume_and_issue(7, 14);

    for (int t = 8; t < TT; t += 8) {
        #pragma unroll
        for (int j = 0; j < 8; ++j) {
            WAIT_VM(12);                          // row t+j DMA complete
            consume_and_issue(j, t + j + 7);
        }
    }
}

extern "C" void kernel_launch(void* const* d_in, const int* in_sizes, int n_in,
                              void* d_out, int out_size, void* d_ws, size_t ws_size,
                              hipStream_t stream) {
    const float* x = (const float*)d_in[0];
    const float* w = (const float*)d_in[1];
    float* out = (float*)d_out;
    // 2048 wave-tiles = 512 blocks x 4 waves; wave-private LDS rings, no barriers.
    pcnn6_kernel<<<dim3(512), dim3(256), 0, stream>>>(x, w, out);
}